// Round 5
// baseline (1120.620 us; speedup 1.0000x reference)
//
#include <hip/hip_runtime.h>

#define IH 128
#define IW 128
#define NPI (IH*IW)   // 16384 pixels per image
// B=2, HEADS=8, D=8, KK=9, ATTN_DIM=72, DIMS={18,36,72}, SD=126

// ---------- K0: build transposed weight tables ----------
// wT[dkk*144 + br*72 + c]   (dc pw weights, both branches)
// pinT[i*144 + j]  = pin_w[j*72 + i]    (144x72 -> i-major)
// pw1T[i*36 + j]   = pw1_w[j*18 + i]    (36x18)
// pw2T[i*72 + j]   = pw2_w[j*36 + i]    (72x36)
// poutT[i*72 + j]  = pout_w[j*72 + i]   (72x72)
__global__ __launch_bounds__(256) void k_wt(const float* __restrict__ w1,
                                            const float* __restrict__ w2,
                                            const float* __restrict__ pin_w,
                                            const float* __restrict__ pw1_w,
                                            const float* __restrict__ pw2_w,
                                            const float* __restrict__ pout_w,
                                            float* __restrict__ wT,
                                            float* __restrict__ pinT,
                                            float* __restrict__ pw1T,
                                            float* __restrict__ pw2T,
                                            float* __restrict__ poutT) {
  int i = blockIdx.x * 256 + threadIdx.x;
  if (i < 5184) {                       // dc pw: 72x72, both branches
    int c = i / 72, dkk = i % 72;
    wT[dkk * 144 + c]      = w1[i];
    wT[dkk * 144 + 72 + c] = w2[i];
  } else if (i < 5184 + 10368) {        // pin 144x72
    int f = i - 5184;
    pinT[(f % 72) * 144 + f / 72] = pin_w[f];
  } else if (i < 5184 + 10368 + 648) {  // pw1 36x18
    int f = i - 5184 - 10368;
    pw1T[(f % 18) * 36 + f / 18] = pw1_w[f];
  } else if (i < 5184 + 10368 + 648 + 2592) {  // pw2 72x36
    int f = i - 5184 - 10368 - 648;
    pw2T[(f % 36) * 72 + f / 36] = pw2_w[f];
  } else if (i < 5184 + 10368 + 648 + 2592 + 5184) {  // pout 72x72
    int f = i - 5184 - 10368 - 648 - 2592;
    poutT[(f % 72) * 72 + f / 72] = pout_w[f];
  }
}

// ---------- K1: qkv GEMM, 512 thr, acc[24], LDS x-chunks ----------
__global__ __launch_bounds__(512) void k_qkv(const float* __restrict__ x,
                                             const float* __restrict__ w,
                                             const float* __restrict__ bias,
                                             float* __restrict__ f) {
  __shared__ float xs[64][65];          // pad 65 -> conflict-free column reads
  int t = threadIdx.x;
  int lane = t & 63;
  int wv = t >> 6;                      // 0..7
  int p0 = blockIdx.x * 64;
  int b = p0 >> 14;
  int pp = p0 & (NPI - 1);
  int jbase = wv * 24;
  float acc[24];
#pragma unroll
  for (int jj = 0; jj < 24; ++jj) acc[jj] = bias[jbase + jj];
  int spx = t >> 3;                     // staging: thread -> (row, 8 floats)
  int sc = (t & 7) * 8;
#pragma unroll 1
  for (int c0 = 0; c0 < 256; c0 += 64) {
    // stage 64 px x 64 ch, coalesced
    float4 va = *reinterpret_cast<const float4*>(x + (size_t)(p0 + spx) * 256 + c0 + sc);
    float4 vb = *reinterpret_cast<const float4*>(x + (size_t)(p0 + spx) * 256 + c0 + sc + 4);
    xs[spx][sc + 0] = va.x; xs[spx][sc + 1] = va.y; xs[spx][sc + 2] = va.z; xs[spx][sc + 3] = va.w;
    xs[spx][sc + 4] = vb.x; xs[spx][sc + 5] = vb.y; xs[spx][sc + 6] = vb.z; xs[spx][sc + 7] = vb.w;
    __syncthreads();
#pragma unroll 1
    for (int cc = 0; cc < 64; cc += 8) {
      float xr[8];
#pragma unroll
      for (int u = 0; u < 8; ++u) xr[u] = xs[lane][cc + u];
#pragma unroll
      for (int u = 0; u < 8; ++u) {
        const float* wp = w + (size_t)(c0 + cc + u) * 192 + jbase;  // uniform -> s_load
#pragma unroll
        for (int jj = 0; jj < 24; ++jj)
          acc[jj] = __builtin_fmaf(xr[u], wp[jj], acc[jj]);
      }
    }
    __syncthreads();
  }
#pragma unroll
  for (int jj = 0; jj < 24; ++jj)
    f[((size_t)(b * 192 + jbase + jj)) * NPI + pp + lane] = acc[jj];
}

// ---------- K2/K8: dep() fused with consumer, 512 thr, acc[36] ----------
// MODE 0: k-path -> softmax -> attn1 ; MODE 1: v-path -> (gout+attn1)*v
template <int MODE>
__global__ __launch_bounds__(512) void k_dep(const float* __restrict__ f,
    const float* __restrict__ dwW1, const float* __restrict__ dwB1,
    const float* __restrict__ dwW2, const float* __restrict__ dwB2,
    const float* __restrict__ wT,  const float* __restrict__ pwB1,
    const float* __restrict__ pwB2, const float* __restrict__ rpb,
    const float* __restrict__ gout, const float* __restrict__ attn_in,
    float* __restrict__ outp) {
  __shared__ float kin[8][20][20];
  __shared__ float dwa[8][18][20];
  __shared__ float dwb[8][18][20];
  __shared__ float spart[256][11];      // MODE0 cross-half partial dots (pad 11)
  int t = threadIdx.x;
  int tile = blockIdx.x;
  int bh = blockIdx.y;
  int h = bh & 7;
  int y0 = (tile >> 3) << 4, x0 = (tile & 7) << 4;
  const float* src = f + ((size_t)(bh * 24 + (MODE ? 16 : 8))) * NPI;
  for (int idx = t; idx < 8 * 20 * 20; idx += 512) {
    int c = idx / 400, r = idx % 400, yy = r / 20, xx = r % 20;
    int ay = y0 - 2 + yy, ax = x0 - 2 + xx;
    float v = 0.f;
    if ((unsigned)ay < (unsigned)IH && (unsigned)ax < (unsigned)IW)
      v = src[c * NPI + ay * IW + ax];
    kin[c][yy][xx] = v;
  }
  __syncthreads();
  for (int idx = t; idx < 8 * 18 * 18; idx += 512) {
    int c = idx / 324, r = idx % 324, yy = r / 18, xx = r % 18;
    int ay = y0 - 1 + yy, ax = x0 - 1 + xx;
    float va = 0.f, vb = 0.f;
    if ((unsigned)ay < (unsigned)IH && (unsigned)ax < (unsigned)IW) {
      va = dwB1[c]; vb = dwB2[c];
#pragma unroll
      for (int ky = 0; ky < 3; ++ky)
#pragma unroll
        for (int kx = 0; kx < 3; ++kx) {
          float s = kin[c][yy + ky][xx + kx];
          va = __builtin_fmaf(dwW1[c * 9 + ky * 3 + kx], s, va);
          vb = __builtin_fmaf(dwW2[c * 9 + ky * 3 + kx], s, vb);
        }
    }
    dwa[c][yy][xx] = va;
    dwb[c][yy][xx] = vb;
  }
  __syncthreads();
  int half = t >> 8;                    // 0: c 0..35 (d 0..3) | 1: c 36..71 (d 4..7)
  int c0 = half * 36;
  int pxl = t & 255;
  int ly = pxl >> 4, lx = pxl & 15;
  int p = (y0 + ly) * IW + (x0 + lx);
  float acc[36];
#pragma unroll
  for (int c = 0; c < 36; ++c) {
    acc[c] = pwB1[c0 + c] + pwB2[c0 + c];
    if (MODE == 0) acc[c] += rpb[h * 9 + (c % 9)];
  }
  // hoist epilogue global loads (latency overlap with FMA stream)
  float q[4]; float coef[9];
  if (MODE == 0) {
#pragma unroll
    for (int dd = 0; dd < 4; ++dd)
      q[dd] = f[((size_t)(bh * 24 + half * 4 + dd)) * NPI + p];
  } else {
#pragma unroll
    for (int kk = 0; kk < 9; ++kk)
      coef[kk] = gout[((size_t)(bh * 9 + kk)) * NPI + p] +
                 attn_in[((size_t)(bh * 9 + kk)) * NPI + p];
  }
#pragma unroll 1
  for (int d = 0; d < 8; ++d) {
#pragma unroll 1
    for (int ky = 0; ky < 3; ++ky) {
      const float* wrow = wT + (size_t)(d * 9 + ky * 3) * 144 + c0;
#pragma unroll
      for (int kx = 0; kx < 3; ++kx) {
        float v1 = dwa[d][ly + ky][lx + kx];
        float v2 = dwb[d][ly + ky][lx + kx];
        const float* wp = wrow + kx * 144;   // uniform -> s_load
#pragma unroll
        for (int c = 0; c < 36; ++c) {
          acc[c] = __builtin_fmaf(wp[c], v1, acc[c]);
          acc[c] = __builtin_fmaf(wp[72 + c], v2, acc[c]);
        }
      }
    }
  }
  if (MODE == 0) {
    float part[9];
#pragma unroll
    for (int kk = 0; kk < 9; ++kk) {
      float s = 0.f;
#pragma unroll
      for (int dd = 0; dd < 4; ++dd) s = __builtin_fmaf(q[dd], acc[dd * 9 + kk], s);
      part[kk] = s;
    }
    if (half) {
#pragma unroll
      for (int kk = 0; kk < 9; ++kk) spart[pxl][kk] = part[kk];
    }
    __syncthreads();
    if (!half) {
      float e[9];
      float m = -1e30f;
#pragma unroll
      for (int kk = 0; kk < 9; ++kk) {
        float s = part[kk] + spart[pxl][kk];
        e[kk] = s;
        m = fmaxf(m, s);
      }
      float sum = 0.f;
#pragma unroll
      for (int kk = 0; kk < 9; ++kk) { e[kk] = __expf(e[kk] - m); sum += e[kk]; }
      float r = 1.f / sum;
#pragma unroll
      for (int kk = 0; kk < 9; ++kk)
        outp[((size_t)(bh * 9 + kk)) * NPI + p] = e[kk] * r;
    }
  } else {
#pragma unroll
    for (int dd = 0; dd < 4; ++dd) {
      float s = 0.f;
#pragma unroll
      for (int kk = 0; kk < 9; ++kk) s = __builtin_fmaf(coef[kk], acc[dd * 9 + kk], s);
      outp[((size_t)(bh * 8 + half * 4 + dd)) * NPI + p] = s;
    }
  }
}

// ---------- K3: pin 1x1 conv 72->144, i-interleaved, acc[36] ----------
__global__ __launch_bounds__(256) void k_pin(const float* __restrict__ attn,
                                             const float* __restrict__ pinT,
                                             const float* __restrict__ bias,
                                             float* __restrict__ fused) {
  int t = threadIdx.x, lane = t & 63;
  int wv = t >> 6;
  int gp = blockIdx.x * 64 + lane;
  int b = gp >> 14, p = gp & (NPI - 1);
  const float* ap = attn + (size_t)b * 72 * NPI + p;
  int jbase = wv * 36;
  float acc[36];
#pragma unroll
  for (int jj = 0; jj < 36; ++jj) acc[jj] = bias[jbase + jj];
#pragma unroll 2
  for (int i = 0; i < 72; ++i) {
    float ai = ap[(size_t)i * NPI];
    const float* wp = pinT + i * 144 + jbase;   // uniform -> s_load
#pragma unroll
    for (int jj = 0; jj < 36; ++jj)
      acc[jj] = __builtin_fmaf(wp[jj], ai, acc[jj]);
  }
#pragma unroll
  for (int jj = 0; jj < 36; ++jj)
    fused[((size_t)b * 144 + jbase + jj) * NPI + p] = acc[jj];
}

// ---------- K4: fused depthwise 7->relu->5->relu->3, 32x32 tiles ----------
__global__ __launch_bounds__(256) void k_dwchain(const float* __restrict__ fused,
    const float* __restrict__ w7, const float* __restrict__ b7,
    const float* __restrict__ w5, const float* __restrict__ b5,
    const float* __restrict__ w3, const float* __restrict__ b3,
    float* __restrict__ dwout) {
  __shared__ float s_in[44][44];
  __shared__ float s_t7[38][38];
  __shared__ float s_t5[34][34];
  int t = threadIdx.x;
  int tile = blockIdx.x;           // 0..15
  int c = blockIdx.y;              // 0..125
  int b = blockIdx.z;
  int y0 = (tile >> 2) << 5, x0 = (tile & 3) << 5;
  const float* src = fused + ((size_t)b * 144 + 18 + c) * NPI;
  for (int idx = t; idx < 44 * 44; idx += 256) {
    int yy = idx / 44, xx = idx % 44;
    int ay = y0 - 6 + yy, ax = x0 - 6 + xx;
    s_in[yy][xx] = ((unsigned)ay < (unsigned)IH && (unsigned)ax < (unsigned)IW)
                       ? src[ay * IW + ax] : 0.f;
  }
  __syncthreads();
  for (int idx = t; idx < 38 * 38; idx += 256) {
    int yy = idx / 38, xx = idx % 38;
    int ay = y0 - 3 + yy, ax = x0 - 3 + xx;
    float s = 0.f;
    if ((unsigned)ay < (unsigned)IH && (unsigned)ax < (unsigned)IW) {
      s = b7[c];
#pragma unroll
      for (int ky = 0; ky < 7; ++ky)
#pragma unroll
        for (int kx = 0; kx < 7; ++kx)
          s = __builtin_fmaf(w7[c * 49 + ky * 7 + kx], s_in[yy + ky][xx + kx], s);
      s = fmaxf(s, 0.f);
    }
    s_t7[yy][xx] = s;
  }
  __syncthreads();
  for (int idx = t; idx < 34 * 34; idx += 256) {
    int yy = idx / 34, xx = idx % 34;
    int ay = y0 - 1 + yy, ax = x0 - 1 + xx;
    float s = 0.f;
    if ((unsigned)ay < (unsigned)IH && (unsigned)ax < (unsigned)IW) {
      s = b5[c];
#pragma unroll
      for (int ky = 0; ky < 5; ++ky)
#pragma unroll
        for (int kx = 0; kx < 5; ++kx)
          s = __builtin_fmaf(w5[c * 25 + ky * 5 + kx], s_t7[yy + ky][xx + kx], s);
      s = fmaxf(s, 0.f);
    }
    s_t5[yy][xx] = s;
  }
  __syncthreads();
  for (int idx = t; idx < 32 * 32; idx += 256) {
    int py = idx >> 5, px = idx & 31;
    float s = b3[c];
#pragma unroll
    for (int ky = 0; ky < 3; ++ky)
#pragma unroll
      for (int kx = 0; kx < 3; ++kx)
        s = __builtin_fmaf(w3[c * 9 + ky * 3 + kx], s_t5[py + ky][px + kx], s);
    dwout[((size_t)b * 126 + c) * NPI + (y0 + py) * IW + (x0 + px)] = s;
  }
}

// ---------- K5: fused gate chain, i-interleaved phases, acc[<=18] ----------
__global__ __launch_bounds__(256) void k_gchain(const float* __restrict__ fused,
    const float* __restrict__ dw,
    const float* __restrict__ pw1T, const float* __restrict__ pw1_b,
    const float* __restrict__ pw2T, const float* __restrict__ pw2_b,
    const float* __restrict__ poutT, const float* __restrict__ pout_b,
    float* __restrict__ gout) {
  __shared__ float t36[36][64];
  __shared__ float t72[72][64];
  int t = threadIdx.x, lane = t & 63;
  int wv = t >> 6;
  int gp = blockIdx.x * 64 + lane;
  int b = gp >> 14, p = gp & (NPI - 1);
  const float* fu = fused + (size_t)b * 144 * NPI + p;
  const float* dp = dw + (size_t)b * 126 * NPI + p;
  // phase A: g1 = pwa*d0 ; t36 = (pw1 g1 + b) * d1
  {
    int j0 = wv * 9;
    float acc[9];
#pragma unroll
    for (int j = 0; j < 9; ++j) acc[j] = pw1_b[j0 + j];
#pragma unroll
    for (int i = 0; i < 18; ++i) {
      float g1 = fu[(size_t)i * NPI] * dp[(size_t)i * NPI];
      const float* wp = pw1T + i * 36 + j0;    // uniform -> s_load
#pragma unroll
      for (int j = 0; j < 9; ++j) acc[j] = __builtin_fmaf(wp[j], g1, acc[j]);
    }
#pragma unroll
    for (int j = 0; j < 9; ++j)
      t36[j0 + j][lane] = acc[j] * dp[(size_t)(18 + j0 + j) * NPI];
  }
  __syncthreads();
  // phase B: t72 = (pw2 t36 + b) * d2
  {
    int j0 = wv * 18;
    float acc[18];
#pragma unroll
    for (int j = 0; j < 18; ++j) acc[j] = pw2_b[j0 + j];
#pragma unroll 2
    for (int i = 0; i < 36; ++i) {
      float ai = t36[i][lane];
      const float* wp = pw2T + i * 72 + j0;    // uniform -> s_load
#pragma unroll
      for (int j = 0; j < 18; ++j) acc[j] = __builtin_fmaf(wp[j], ai, acc[j]);
    }
#pragma unroll
    for (int j = 0; j < 18; ++j)
      t72[j0 + j][lane] = acc[j] * dp[(size_t)(54 + j0 + j) * NPI];
  }
  __syncthreads();
  // phase C: gout = pout t72 + b
  {
    int j0 = wv * 18;
    float acc[18];
#pragma unroll
    for (int j = 0; j < 18; ++j) acc[j] = pout_b[j0 + j];
#pragma unroll 2
    for (int i = 0; i < 72; ++i) {
      float ai = t72[i][lane];
      const float* wp = poutT + i * 72 + j0;   // uniform -> s_load
#pragma unroll
      for (int j = 0; j < 18; ++j) acc[j] = __builtin_fmaf(wp[j], ai, acc[j]);
    }
#pragma unroll
    for (int j = 0; j < 18; ++j)
      gout[((size_t)b * 72 + j0 + j) * NPI + p] = acc[j];
  }
}

// ---------- K9: proj GEMM, lane=co, acc[16 px], uniform pre via s_load ----------
__global__ __launch_bounds__(256) void k_proj(const float* __restrict__ pre,
                                              const float* __restrict__ w,
                                              const float* __restrict__ bias,
                                              float* __restrict__ out) {
  int t = threadIdx.x;                 // output channel 0..255
  int blk = blockIdx.x;                // 2048 blocks x 16 px
  int b = (blk * 16) >> 14;
  int p0 = (blk * 16) & (NPI - 1);
  const float* pp = pre + (size_t)b * 64 * NPI + p0;
  float acc[16];
  float bs = bias[t];
#pragma unroll
  for (int px = 0; px < 16; ++px) acc[px] = bs;
#pragma unroll 2
  for (int i = 0; i < 64; ++i) {
    float wv = w[i * 256 + t];                  // per-lane coalesced
    const float* sp = pp + (size_t)i * NPI;     // uniform -> s_load_dwordx16
#pragma unroll
    for (int px = 0; px < 16; ++px)
      acc[px] = __builtin_fmaf(wv, sp[px], acc[px]);
  }
#pragma unroll
  for (int px = 0; px < 16; ++px)
    out[((size_t)(b * NPI + p0 + px)) * 256 + t] = acc[px];
}

extern "C" void kernel_launch(void* const* d_in, const int* in_sizes, int n_in,
                              void* d_out, int out_size, void* d_ws, size_t ws_size,
                              hipStream_t stream) {
  const float* x        = (const float*)d_in[0];
  const float* qkv_w    = (const float*)d_in[1];
  const float* qkv_b    = (const float*)d_in[2];
  const float* dc1_dw_w = (const float*)d_in[3];
  const float* dc1_dw_b = (const float*)d_in[4];
  const float* dc1_pw_w = (const float*)d_in[5];
  const float* dc1_pw_b = (const float*)d_in[6];
  const float* dc2_dw_w = (const float*)d_in[7];
  const float* dc2_dw_b = (const float*)d_in[8];
  const float* dc2_pw_w = (const float*)d_in[9];
  const float* dc2_pw_b = (const float*)d_in[10];
  const float* rpb      = (const float*)d_in[11];
  const float* pin_w    = (const float*)d_in[12];
  const float* pin_b    = (const float*)d_in[13];
  const float* dw7_w    = (const float*)d_in[14];
  const float* dw7_b    = (const float*)d_in[15];
  const float* dw5_w    = (const float*)d_in[16];
  const float* dw5_b    = (const float*)d_in[17];
  const float* dw3_w    = (const float*)d_in[18];
  const float* dw3_b    = (const float*)d_in[19];
  const float* pw1_w    = (const float*)d_in[20];
  const float* pw1_b    = (const float*)d_in[21];
  const float* pw2_w    = (const float*)d_in[22];
  const float* pw2_b    = (const float*)d_in[23];
  const float* pout_w   = (const float*)d_in[24];
  const float* pout_b   = (const float*)d_in[25];
  const float* proj_w   = (const float*)d_in[26];
  const float* proj_b   = (const float*)d_in[27];
  (void)in_sizes; (void)n_in; (void)out_size; (void)ws_size;

  float* fbuf = (float*)d_out;          // qkv planar tensor, consumed before proj writes
  float* ws    = (float*)d_ws;
  float* wT    = ws;                    // 10368
  float* pinT  = wT + 10368;            // 10368
  float* pw1T  = pinT + 10368;          // 648
  float* pw2T  = pw1T + 648;            // 2592
  float* poutT = pw2T + 2592;           // 5184
  float* attn1 = poutT + 5184;          // 2359296
  float* fused = attn1 + 2359296;       // 4718592
  float* dwout = fused + 4718592;       // 4128768
  float* goutb = dwout + 4128768;       // 2359296
  float* pre   = goutb + 2359296;       // 2097152  -> total ~62.8 MB

  hipLaunchKernelGGL(k_wt, dim3(94), dim3(256), 0, stream, dc1_pw_w, dc2_pw_w,
                     pin_w, pw1_w, pw2_w, pout_w, wT, pinT, pw1T, pw2T, poutT);
  hipLaunchKernelGGL(k_qkv, dim3(512), dim3(512), 0, stream, x, qkv_w, qkv_b, fbuf);
  hipLaunchKernelGGL((k_dep<0>), dim3(64, 16), dim3(512), 0, stream, fbuf,
                     dc1_dw_w, dc1_dw_b, dc2_dw_w, dc2_dw_b, wT, dc1_pw_b, dc2_pw_b,
                     rpb, (const float*)nullptr, (const float*)nullptr, attn1);
  hipLaunchKernelGGL(k_pin, dim3(512), dim3(256), 0, stream, attn1, pinT, pin_b, fused);
  hipLaunchKernelGGL(k_dwchain, dim3(16, 126, 2), dim3(256), 0, stream, fused,
                     dw7_w, dw7_b, dw5_w, dw5_b, dw3_w, dw3_b, dwout);
  hipLaunchKernelGGL(k_gchain, dim3(512), dim3(256), 0, stream, fused, dwout,
                     pw1T, pw1_b, pw2T, pw2_b, poutT, pout_b, goutb);
  hipLaunchKernelGGL((k_dep<1>), dim3(64, 16), dim3(512), 0, stream, fbuf,
                     dc1_dw_w, dc1_dw_b, dc2_dw_w, dc2_dw_b, wT, dc1_pw_b, dc2_pw_b,
                     rpb, goutb, attn1, pre);
  hipLaunchKernelGGL(k_proj, dim3(2048), dim3(256), 0, stream, pre, proj_w, proj_b,
                     (float*)d_out);
}

// Round 8
// 724.264 us; speedup vs baseline: 1.5473x; 1.5473x over previous
//
#include <hip/hip_runtime.h>

#define IH 128
#define IW 128
#define NPI (IH*IW)   // 16384 pixels per image
// B=2, HEADS=8, D=8, KK=9, ATTN_DIM=72, DIMS={18,36,72}, SD=126

// ---------- K0: build transposed weight tables ----------
__global__ __launch_bounds__(256) void k_wt(const float* __restrict__ w1,
                                            const float* __restrict__ w2,
                                            const float* __restrict__ pin_w,
                                            const float* __restrict__ pw1_w,
                                            const float* __restrict__ pw2_w,
                                            const float* __restrict__ pout_w,
                                            float* __restrict__ wT,
                                            float* __restrict__ pinT,
                                            float* __restrict__ pw1T,
                                            float* __restrict__ pw2T,
                                            float* __restrict__ poutT) {
  int i = blockIdx.x * 256 + threadIdx.x;
  if (i < 5184) {                       // dc pw: 72x72, both branches
    int c = i / 72, dkk = i % 72;
    wT[dkk * 144 + c]      = w1[i];
    wT[dkk * 144 + 72 + c] = w2[i];
  } else if (i < 5184 + 10368) {        // pin 144x72
    int f = i - 5184;
    pinT[(f % 72) * 144 + f / 72] = pin_w[f];
  } else if (i < 5184 + 10368 + 648) {  // pw1 36x18
    int f = i - 5184 - 10368;
    pw1T[(f % 18) * 36 + f / 18] = pw1_w[f];
  } else if (i < 5184 + 10368 + 648 + 2592) {  // pw2 72x36
    int f = i - 5184 - 10368 - 648;
    pw2T[(f % 36) * 72 + f / 36] = pw2_w[f];
  } else if (i < 5184 + 10368 + 648 + 2592 + 5184) {  // pout 72x72
    int f = i - 5184 - 10368 - 648 - 2592;
    poutT[(f % 72) * 72 + f / 72] = pout_w[f];
  }
}

// ---------- K1: qkv GEMM, 512 thr, acc[24], LDS x-chunks ----------
__global__ __launch_bounds__(512) void k_qkv(const float* __restrict__ x,
                                             const float* __restrict__ w,
                                             const float* __restrict__ bias,
                                             float* __restrict__ f) {
  __shared__ float xs[64][65];          // pad 65 -> conflict-free column reads
  int t = threadIdx.x;
  int lane = t & 63;
  int wv = t >> 6;                      // 0..7
  int p0 = blockIdx.x * 64;
  int b = p0 >> 14;
  int pp = p0 & (NPI - 1);
  int jbase = wv * 24;
  float acc[24];
#pragma unroll
  for (int jj = 0; jj < 24; ++jj) acc[jj] = bias[jbase + jj];
  int spx = t >> 3;                     // staging: thread -> (row, 8 floats)
  int sc = (t & 7) * 8;
#pragma unroll 1
  for (int c0 = 0; c0 < 256; c0 += 64) {
    // stage 64 px x 64 ch, coalesced
    float4 va = *reinterpret_cast<const float4*>(x + (size_t)(p0 + spx) * 256 + c0 + sc);
    float4 vb = *reinterpret_cast<const float4*>(x + (size_t)(p0 + spx) * 256 + c0 + sc + 4);
    xs[spx][sc + 0] = va.x; xs[spx][sc + 1] = va.y; xs[spx][sc + 2] = va.z; xs[spx][sc + 3] = va.w;
    xs[spx][sc + 4] = vb.x; xs[spx][sc + 5] = vb.y; xs[spx][sc + 6] = vb.z; xs[spx][sc + 7] = vb.w;
    __syncthreads();
#pragma unroll 1
    for (int cc = 0; cc < 64; cc += 8) {
      float xr[8];
#pragma unroll
      for (int u = 0; u < 8; ++u) xr[u] = xs[lane][cc + u];
#pragma unroll
      for (int u = 0; u < 8; ++u) {
        const float* wp = w + (size_t)(c0 + cc + u) * 192 + jbase;  // uniform -> s_load
#pragma unroll
        for (int jj = 0; jj < 24; ++jj)
          acc[jj] = __builtin_fmaf(xr[u], wp[jj], acc[jj]);
      }
    }
    __syncthreads();
  }
#pragma unroll
  for (int jj = 0; jj < 24; ++jj)
    f[((size_t)(b * 192 + jbase + jj)) * NPI + pp + lane] = acc[jj];
}

// ---------- K2/K8: dep() fused with consumer ----------
// Round-1 structure: 256 thr, 1 px/thread, acc[72] (144-FMA bursts per s_load batch).
// (256,2): allow up to 256 VGPR -> no scratch spill (round-1 showed 11MB spill at VGPR=52).
template <int MODE>
__global__ __launch_bounds__(256, 2) void k_dep(const float* __restrict__ f,
    const float* __restrict__ dwW1, const float* __restrict__ dwB1,
    const float* __restrict__ dwW2, const float* __restrict__ dwB2,
    const float* __restrict__ wT,  const float* __restrict__ pwB1,
    const float* __restrict__ pwB2, const float* __restrict__ rpb,
    const float* __restrict__ gout, const float* __restrict__ attn_in,
    float* __restrict__ outp) {
  __shared__ float kin[8][20][20];
  __shared__ float dwa[8][18][20];   // pad stride 20 (2-way conflicts are free)
  __shared__ float dwb[8][18][20];
  int t = threadIdx.x;
  int tile = blockIdx.x;
  int bh = blockIdx.y;
  int h = bh & 7;
  int y0 = (tile >> 3) << 4, x0 = (tile & 7) << 4;
  const float* src = f + ((size_t)(bh * 24 + (MODE ? 16 : 8))) * NPI;
  for (int idx = t; idx < 8 * 20 * 20; idx += 256) {
    int c = idx / 400, r = idx % 400, yy = r / 20, xx = r % 20;
    int ay = y0 - 2 + yy, ax = x0 - 2 + xx;
    float v = 0.f;
    if ((unsigned)ay < (unsigned)IH && (unsigned)ax < (unsigned)IW)
      v = src[c * NPI + ay * IW + ax];
    kin[c][yy][xx] = v;
  }
  __syncthreads();
  for (int idx = t; idx < 8 * 18 * 18; idx += 256) {
    int c = idx / 324, r = idx % 324, yy = r / 18, xx = r % 18;
    int ay = y0 - 1 + yy, ax = x0 - 1 + xx;
    float va = 0.f, vb = 0.f;
    if ((unsigned)ay < (unsigned)IH && (unsigned)ax < (unsigned)IW) {
      va = dwB1[c]; vb = dwB2[c];
#pragma unroll
      for (int ky = 0; ky < 3; ++ky)
#pragma unroll
        for (int kx = 0; kx < 3; ++kx) {
          float s = kin[c][yy + ky][xx + kx];
          va = __builtin_fmaf(dwW1[c * 9 + ky * 3 + kx], s, va);
          vb = __builtin_fmaf(dwW2[c * 9 + ky * 3 + kx], s, vb);
        }
    }
    dwa[c][yy][xx] = va;
    dwb[c][yy][xx] = vb;
  }
  __syncthreads();
  int ly = t >> 4, lx = t & 15;
  int p = (y0 + ly) * IW + (x0 + lx);
  float acc[72];
#pragma unroll
  for (int c = 0; c < 72; ++c) {
    acc[c] = pwB1[c] + pwB2[c];
    if (MODE == 0) acc[c] += rpb[h * 9 + (c % 9)];
  }
  // hoist epilogue global loads (latency overlap with FMA stream)
  float q[8]; float coef[9];
  if (MODE == 0) {
#pragma unroll
    for (int d = 0; d < 8; ++d) q[d] = f[((size_t)(bh * 24 + d)) * NPI + p];
  } else {
#pragma unroll
    for (int kk = 0; kk < 9; ++kk)
      coef[kk] = gout[((size_t)(bh * 9 + kk)) * NPI + p] +
                 attn_in[((size_t)(bh * 9 + kk)) * NPI + p];
  }
#pragma unroll 1
  for (int d = 0; d < 8; ++d) {
#pragma unroll
    for (int t9 = 0; t9 < 9; ++t9) {               // static ky/kx, no div/mod
      const int ky = t9 / 3, kx = t9 % 3;
      const float v1 = dwa[d][ly + ky][lx + kx];
      const float v2 = dwb[d][ly + ky][lx + kx];
      const float* wp = wT + (size_t)(d * 9 + t9) * 144;   // uniform -> s_load
#pragma unroll
      for (int c = 0; c < 72; ++c) {               // 144-FMA burst per batch
        acc[c] = __builtin_fmaf(wp[c], v1, acc[c]);
        acc[c] = __builtin_fmaf(wp[72 + c], v2, acc[c]);
      }
    }
  }
  if (MODE == 0) {
    float e[9];
    float m = -1e30f;
#pragma unroll
    for (int kk = 0; kk < 9; ++kk) {
      float s = 0.f;
#pragma unroll
      for (int d = 0; d < 8; ++d) s = __builtin_fmaf(q[d], acc[d * 9 + kk], s);
      e[kk] = s;
      m = fmaxf(m, s);
    }
    float sum = 0.f;
#pragma unroll
    for (int kk = 0; kk < 9; ++kk) { e[kk] = __expf(e[kk] - m); sum += e[kk]; }
    float r = 1.f / sum;
#pragma unroll
    for (int kk = 0; kk < 9; ++kk)
      outp[((size_t)(bh * 9 + kk)) * NPI + p] = e[kk] * r;
  } else {
#pragma unroll
    for (int d = 0; d < 8; ++d) {
      float s = 0.f;
#pragma unroll
      for (int kk = 0; kk < 9; ++kk) s = __builtin_fmaf(coef[kk], acc[d * 9 + kk], s);
      outp[((size_t)(bh * 8 + d)) * NPI + p] = s;
    }
  }
}

// ---------- K3: pin 1x1 conv 72->144, i-interleaved, acc[36] ----------
__global__ __launch_bounds__(256, 2) void k_pin(const float* __restrict__ attn,
                                                const float* __restrict__ pinT,
                                                const float* __restrict__ bias,
                                                float* __restrict__ fused) {
  int t = threadIdx.x, lane = t & 63;
  int wv = t >> 6;
  int gp = blockIdx.x * 64 + lane;
  int b = gp >> 14, p = gp & (NPI - 1);
  const float* ap = attn + (size_t)b * 72 * NPI + p;
  int jbase = wv * 36;
  float acc[36];
#pragma unroll
  for (int jj = 0; jj < 36; ++jj) acc[jj] = bias[jbase + jj];
#pragma unroll 2
  for (int i = 0; i < 72; ++i) {
    float ai = ap[(size_t)i * NPI];
    const float* wp = pinT + i * 144 + jbase;   // uniform -> s_load
#pragma unroll
    for (int jj = 0; jj < 36; ++jj)
      acc[jj] = __builtin_fmaf(wp[jj], ai, acc[jj]);
  }
#pragma unroll
  for (int jj = 0; jj < 36; ++jj)
    fused[((size_t)b * 144 + jbase + jj) * NPI + p] = acc[jj];
}

// ---------- K4: fused depthwise 7->relu->5->relu->3, 32x32 tiles ----------
__global__ __launch_bounds__(256) void k_dwchain(const float* __restrict__ fused,
    const float* __restrict__ w7, const float* __restrict__ b7,
    const float* __restrict__ w5, const float* __restrict__ b5,
    const float* __restrict__ w3, const float* __restrict__ b3,
    float* __restrict__ dwout) {
  __shared__ float s_in[44][44];
  __shared__ float s_t7[38][38];
  __shared__ float s_t5[34][34];
  int t = threadIdx.x;
  int tile = blockIdx.x;           // 0..15
  int c = blockIdx.y;              // 0..125
  int b = blockIdx.z;
  int y0 = (tile >> 2) << 5, x0 = (tile & 3) << 5;
  const float* src = fused + ((size_t)b * 144 + 18 + c) * NPI;
  for (int idx = t; idx < 44 * 44; idx += 256) {
    int yy = idx / 44, xx = idx % 44;
    int ay = y0 - 6 + yy, ax = x0 - 6 + xx;
    s_in[yy][xx] = ((unsigned)ay < (unsigned)IH && (unsigned)ax < (unsigned)IW)
                       ? src[ay * IW + ax] : 0.f;
  }
  __syncthreads();
  for (int idx = t; idx < 38 * 38; idx += 256) {
    int yy = idx / 38, xx = idx % 38;
    int ay = y0 - 3 + yy, ax = x0 - 3 + xx;
    float s = 0.f;
    if ((unsigned)ay < (unsigned)IH && (unsigned)ax < (unsigned)IW) {
      s = b7[c];
#pragma unroll
      for (int ky = 0; ky < 7; ++ky)
#pragma unroll
        for (int kx = 0; kx < 7; ++kx)
          s = __builtin_fmaf(w7[c * 49 + ky * 7 + kx], s_in[yy + ky][xx + kx], s);
      s = fmaxf(s, 0.f);
    }
    s_t7[yy][xx] = s;
  }
  __syncthreads();
  for (int idx = t; idx < 34 * 34; idx += 256) {
    int yy = idx / 34, xx = idx % 34;
    int ay = y0 - 1 + yy, ax = x0 - 1 + xx;
    float s = 0.f;
    if ((unsigned)ay < (unsigned)IH && (unsigned)ax < (unsigned)IW) {
      s = b5[c];
#pragma unroll
      for (int ky = 0; ky < 5; ++ky)
#pragma unroll
        for (int kx = 0; kx < 5; ++kx)
          s = __builtin_fmaf(w5[c * 25 + ky * 5 + kx], s_t7[yy + ky][xx + kx], s);
      s = fmaxf(s, 0.f);
    }
    s_t5[yy][xx] = s;
  }
  __syncthreads();
  for (int idx = t; idx < 32 * 32; idx += 256) {
    int py = idx >> 5, px = idx & 31;
    float s = b3[c];
#pragma unroll
    for (int ky = 0; ky < 3; ++ky)
#pragma unroll
      for (int kx = 0; kx < 3; ++kx)
        s = __builtin_fmaf(w3[c * 9 + ky * 3 + kx], s_t5[py + ky][px + kx], s);
    dwout[((size_t)b * 126 + c) * NPI + (y0 + py) * IW + (x0 + px)] = s;
  }
}

// ---------- K5: fused gate chain, i-interleaved phases, acc[<=18] ----------
__global__ __launch_bounds__(256, 2) void k_gchain(const float* __restrict__ fused,
    const float* __restrict__ dw,
    const float* __restrict__ pw1T, const float* __restrict__ pw1_b,
    const float* __restrict__ pw2T, const float* __restrict__ pw2_b,
    const float* __restrict__ poutT, const float* __restrict__ pout_b,
    float* __restrict__ gout) {
  __shared__ float t36[36][64];
  __shared__ float t72[72][64];
  int t = threadIdx.x, lane = t & 63;
  int wv = t >> 6;
  int gp = blockIdx.x * 64 + lane;
  int b = gp >> 14, p = gp & (NPI - 1);
  const float* fu = fused + (size_t)b * 144 * NPI + p;
  const float* dp = dw + (size_t)b * 126 * NPI + p;
  // phase A: g1 = pwa*d0 ; t36 = (pw1 g1 + b) * d1
  {
    int j0 = wv * 9;
    float acc[9];
#pragma unroll
    for (int j = 0; j < 9; ++j) acc[j] = pw1_b[j0 + j];
#pragma unroll
    for (int i = 0; i < 18; ++i) {
      float g1 = fu[(size_t)i * NPI] * dp[(size_t)i * NPI];
      const float* wp = pw1T + i * 36 + j0;    // uniform -> s_load
#pragma unroll
      for (int j = 0; j < 9; ++j) acc[j] = __builtin_fmaf(wp[j], g1, acc[j]);
    }
#pragma unroll
    for (int j = 0; j < 9; ++j)
      t36[j0 + j][lane] = acc[j] * dp[(size_t)(18 + j0 + j) * NPI];
  }
  __syncthreads();
  // phase B: t72 = (pw2 t36 + b) * d2
  {
    int j0 = wv * 18;
    float acc[18];
#pragma unroll
    for (int j = 0; j < 18; ++j) acc[j] = pw2_b[j0 + j];
#pragma unroll 2
    for (int i = 0; i < 36; ++i) {
      float ai = t36[i][lane];
      const float* wp = pw2T + i * 72 + j0;    // uniform -> s_load
#pragma unroll
      for (int j = 0; j < 18; ++j) acc[j] = __builtin_fmaf(wp[j], ai, acc[j]);
    }
#pragma unroll
    for (int j = 0; j < 18; ++j)
      t72[j0 + j][lane] = acc[j] * dp[(size_t)(54 + j0 + j) * NPI];
  }
  __syncthreads();
  // phase C: gout = pout t72 + b
  {
    int j0 = wv * 18;
    float acc[18];
#pragma unroll
    for (int j = 0; j < 18; ++j) acc[j] = pout_b[j0 + j];
#pragma unroll 2
    for (int i = 0; i < 72; ++i) {
      float ai = t72[i][lane];
      const float* wp = poutT + i * 72 + j0;   // uniform -> s_load
#pragma unroll
      for (int j = 0; j < 18; ++j) acc[j] = __builtin_fmaf(wp[j], ai, acc[j]);
    }
#pragma unroll
    for (int j = 0; j < 18; ++j)
      gout[((size_t)b * 72 + j0 + j) * NPI + p] = acc[j];
  }
}

// ---------- K9: proj GEMM, lane=co, acc[16 px], uniform pre via s_load ----------
__global__ __launch_bounds__(256, 2) void k_proj(const float* __restrict__ pre,
                                                 const float* __restrict__ w,
                                                 const float* __restrict__ bias,
                                                 float* __restrict__ out) {
  int t = threadIdx.x;                 // output channel 0..255
  int blk = blockIdx.x;                // 2048 blocks x 16 px
  int b = (blk * 16) >> 14;
  int p0 = (blk * 16) & (NPI - 1);
  const float* pp = pre + (size_t)b * 64 * NPI + p0;
  float acc[16];
  float bs = bias[t];
#pragma unroll
  for (int px = 0; px < 16; ++px) acc[px] = bs;
#pragma unroll 2
  for (int i = 0; i < 64; ++i) {
    float wv = w[i * 256 + t];                  // per-lane coalesced
    const float* sp = pp + (size_t)i * NPI;     // uniform -> s_load_dwordx16
#pragma unroll
    for (int px = 0; px < 16; ++px)
      acc[px] = __builtin_fmaf(wv, sp[px], acc[px]);
  }
#pragma unroll
  for (int px = 0; px < 16; ++px)
    out[((size_t)(b * NPI + p0 + px)) * 256 + t] = acc[px];
}

extern "C" void kernel_launch(void* const* d_in, const int* in_sizes, int n_in,
                              void* d_out, int out_size, void* d_ws, size_t ws_size,
                              hipStream_t stream) {
  const float* x        = (const float*)d_in[0];
  const float* qkv_w    = (const float*)d_in[1];
  const float* qkv_b    = (const float*)d_in[2];
  const float* dc1_dw_w = (const float*)d_in[3];
  const float* dc1_dw_b = (const float*)d_in[4];
  const float* dc1_pw_w = (const float*)d_in[5];
  const float* dc1_pw_b = (const float*)d_in[6];
  const float* dc2_dw_w = (const float*)d_in[7];
  const float* dc2_dw_b = (const float*)d_in[8];
  const float* dc2_pw_w = (const float*)d_in[9];
  const float* dc2_pw_b = (const float*)d_in[10];
  const float* rpb      = (const float*)d_in[11];
  const float* pin_w    = (const float*)d_in[12];
  const float* pin_b    = (const float*)d_in[13];
  const float* dw7_w    = (const float*)d_in[14];
  const float* dw7_b    = (const float*)d_in[15];
  const float* dw5_w    = (const float*)d_in[16];
  const float* dw5_b    = (const float*)d_in[17];
  const float* dw3_w    = (const float*)d_in[18];
  const float* dw3_b    = (const float*)d_in[19];
  const float* pw1_w    = (const float*)d_in[20];
  const float* pw1_b    = (const float*)d_in[21];
  const float* pw2_w    = (const float*)d_in[22];
  const float* pw2_b    = (const float*)d_in[23];
  const float* pout_w   = (const float*)d_in[24];
  const float* pout_b   = (const float*)d_in[25];
  const float* proj_w   = (const float*)d_in[26];
  const float* proj_b   = (const float*)d_in[27];
  (void)in_sizes; (void)n_in; (void)out_size; (void)ws_size;

  float* fbuf = (float*)d_out;          // qkv planar tensor, consumed before proj writes
  float* ws    = (float*)d_ws;
  float* wT    = ws;                    // 10368
  float* pinT  = wT + 10368;            // 10368
  float* pw1T  = pinT + 10368;          // 648
  float* pw2T  = pw1T + 648;            // 2592
  float* poutT = pw2T + 2592;           // 5184
  float* attn1 = poutT + 5184;          // 2359296
  float* fused = attn1 + 2359296;       // 4718592
  float* dwout = fused + 4718592;       // 4128768
  float* goutb = dwout + 4128768;       // 2359296
  float* pre   = goutb + 2359296;       // 2097152  -> total ~62.8 MB

  hipLaunchKernelGGL(k_wt, dim3(94), dim3(256), 0, stream, dc1_pw_w, dc2_pw_w,
                     pin_w, pw1_w, pw2_w, pout_w, wT, pinT, pw1T, pw2T, poutT);
  hipLaunchKernelGGL(k_qkv, dim3(512), dim3(512), 0, stream, x, qkv_w, qkv_b, fbuf);
  hipLaunchKernelGGL((k_dep<0>), dim3(64, 16), dim3(256), 0, stream, fbuf,
                     dc1_dw_w, dc1_dw_b, dc2_dw_w, dc2_dw_b, wT, dc1_pw_b, dc2_pw_b,
                     rpb, (const float*)nullptr, (const float*)nullptr, attn1);
  hipLaunchKernelGGL(k_pin, dim3(512), dim3(256), 0, stream, attn1, pinT, pin_b, fused);
  hipLaunchKernelGGL(k_dwchain, dim3(16, 126, 2), dim3(256), 0, stream, fused,
                     dw7_w, dw7_b, dw5_w, dw5_b, dw3_w, dw3_b, dwout);
  hipLaunchKernelGGL(k_gchain, dim3(512), dim3(256), 0, stream, fused, dwout,
                     pw1T, pw1_b, pw2T, pw2_b, poutT, pout_b, goutb);
  hipLaunchKernelGGL((k_dep<1>), dim3(64, 16), dim3(256), 0, stream, fbuf,
                     dc1_dw_w, dc1_dw_b, dc2_dw_w, dc2_dw_b, wT, dc1_pw_b, dc2_pw_b,
                     rpb, goutb, attn1, pre);
  hipLaunchKernelGGL(k_proj, dim3(2048), dim3(256), 0, stream, pre, proj_w, proj_b,
                     (float*)d_out);
}

// Round 9
// 604.938 us; speedup vs baseline: 1.8525x; 1.1973x over previous
//
#include <hip/hip_runtime.h>

#define IH 128
#define IW 128
#define NPI (IH*IW)   // 16384 pixels per image
// B=2, HEADS=8, D=8, KK=9, ATTN_DIM=72, DIMS={18,36,72}, SD=126

// ---------- K0: build transposed weight tables ----------
__global__ __launch_bounds__(256) void k_wt(const float* __restrict__ w1,
                                            const float* __restrict__ w2,
                                            const float* __restrict__ pin_w,
                                            const float* __restrict__ pw1_w,
                                            const float* __restrict__ pw2_w,
                                            const float* __restrict__ pout_w,
                                            float* __restrict__ wT,
                                            float* __restrict__ pinT,
                                            float* __restrict__ pw1T,
                                            float* __restrict__ pw2T,
                                            float* __restrict__ poutT) {
  int i = blockIdx.x * 256 + threadIdx.x;
  if (i < 5184) {                       // dc pw: 72x72, both branches
    int c = i / 72, dkk = i % 72;
    wT[dkk * 144 + c]      = w1[i];
    wT[dkk * 144 + 72 + c] = w2[i];
  } else if (i < 5184 + 10368) {        // pin 144x72
    int f = i - 5184;
    pinT[(f % 72) * 144 + f / 72] = pin_w[f];
  } else if (i < 5184 + 10368 + 648) {  // pw1 36x18
    int f = i - 5184 - 10368;
    pw1T[(f % 18) * 36 + f / 18] = pw1_w[f];
  } else if (i < 5184 + 10368 + 648 + 2592) {  // pw2 72x36
    int f = i - 5184 - 10368 - 648;
    pw2T[(f % 36) * 72 + f / 36] = pw2_w[f];
  } else if (i < 5184 + 10368 + 648 + 2592 + 5184) {  // pout 72x72
    int f = i - 5184 - 10368 - 648 - 2592;
    poutT[(f % 72) * 72 + f / 72] = pout_w[f];
  }
}

// ---------- K1: qkv GEMM, 512 thr, acc[24], LDS x-chunks ----------
__global__ __launch_bounds__(512) void k_qkv(const float* __restrict__ x,
                                             const float* __restrict__ w,
                                             const float* __restrict__ bias,
                                             float* __restrict__ f) {
  __shared__ float xs[64][65];          // pad 65 -> conflict-free column reads
  int t = threadIdx.x;
  int lane = t & 63;
  int wv = t >> 6;                      // 0..7
  int p0 = blockIdx.x * 64;
  int b = p0 >> 14;
  int pp = p0 & (NPI - 1);
  int jbase = wv * 24;
  float acc[24];
#pragma unroll
  for (int jj = 0; jj < 24; ++jj) acc[jj] = bias[jbase + jj];
  int spx = t >> 3;                     // staging: thread -> (row, 8 floats)
  int sc = (t & 7) * 8;
#pragma unroll 1
  for (int c0 = 0; c0 < 256; c0 += 64) {
    // stage 64 px x 64 ch, coalesced
    float4 va = *reinterpret_cast<const float4*>(x + (size_t)(p0 + spx) * 256 + c0 + sc);
    float4 vb = *reinterpret_cast<const float4*>(x + (size_t)(p0 + spx) * 256 + c0 + sc + 4);
    xs[spx][sc + 0] = va.x; xs[spx][sc + 1] = va.y; xs[spx][sc + 2] = va.z; xs[spx][sc + 3] = va.w;
    xs[spx][sc + 4] = vb.x; xs[spx][sc + 5] = vb.y; xs[spx][sc + 6] = vb.z; xs[spx][sc + 7] = vb.w;
    __syncthreads();
#pragma unroll 1
    for (int cc = 0; cc < 64; cc += 8) {
      float xr[8];
#pragma unroll
      for (int u = 0; u < 8; ++u) xr[u] = xs[lane][cc + u];
#pragma unroll
      for (int u = 0; u < 8; ++u) {
        const float* wp = w + (size_t)(c0 + cc + u) * 192 + jbase;  // uniform -> s_load
#pragma unroll
        for (int jj = 0; jj < 24; ++jj)
          acc[jj] = __builtin_fmaf(xr[u], wp[jj], acc[jj]);
      }
    }
    __syncthreads();
  }
#pragma unroll
  for (int jj = 0; jj < 24; ++jj)
    f[((size_t)(b * 192 + jbase + jj)) * NPI + pp + lane] = acc[jj];
}

// ---------- K2/K8: dep() fused with consumer ----------
// 256 thr, 1 px/thread, acc[72], 144-FMA bursts per s_load batch.
// (256,1): lift VGPR cap to 512 so allocator keeps acc[72]+working set (~110-130
// regs) IN REGISTERS instead of spilling (r8: VGPR=72, FETCH +20MB scratch).
// Epilogue loads kept AFTER the FMA loop to minimize live range (round-1 position).
template <int MODE>
__global__ __launch_bounds__(256, 1) void k_dep(const float* __restrict__ f,
    const float* __restrict__ dwW1, const float* __restrict__ dwB1,
    const float* __restrict__ dwW2, const float* __restrict__ dwB2,
    const float* __restrict__ wT,  const float* __restrict__ pwB1,
    const float* __restrict__ pwB2, const float* __restrict__ rpb,
    const float* __restrict__ gout, const float* __restrict__ attn_in,
    float* __restrict__ outp) {
  __shared__ float kin[8][20][20];
  __shared__ float dwa[8][18][20];   // pad stride 20 (2-way conflicts are free)
  __shared__ float dwb[8][18][20];
  int t = threadIdx.x;
  int tile = blockIdx.x;
  int bh = blockIdx.y;
  int h = bh & 7;
  int y0 = (tile >> 3) << 4, x0 = (tile & 7) << 4;
  const float* src = f + ((size_t)(bh * 24 + (MODE ? 16 : 8))) * NPI;
  for (int idx = t; idx < 8 * 20 * 20; idx += 256) {
    int c = idx / 400, r = idx % 400, yy = r / 20, xx = r % 20;
    int ay = y0 - 2 + yy, ax = x0 - 2 + xx;
    float v = 0.f;
    if ((unsigned)ay < (unsigned)IH && (unsigned)ax < (unsigned)IW)
      v = src[c * NPI + ay * IW + ax];
    kin[c][yy][xx] = v;
  }
  __syncthreads();
  for (int idx = t; idx < 8 * 18 * 18; idx += 256) {
    int c = idx / 324, r = idx % 324, yy = r / 18, xx = r % 18;
    int ay = y0 - 1 + yy, ax = x0 - 1 + xx;
    float va = 0.f, vb = 0.f;
    if ((unsigned)ay < (unsigned)IH && (unsigned)ax < (unsigned)IW) {
      va = dwB1[c]; vb = dwB2[c];
#pragma unroll
      for (int ky = 0; ky < 3; ++ky)
#pragma unroll
        for (int kx = 0; kx < 3; ++kx) {
          float s = kin[c][yy + ky][xx + kx];
          va = __builtin_fmaf(dwW1[c * 9 + ky * 3 + kx], s, va);
          vb = __builtin_fmaf(dwW2[c * 9 + ky * 3 + kx], s, vb);
        }
    }
    dwa[c][yy][xx] = va;
    dwb[c][yy][xx] = vb;
  }
  __syncthreads();
  int ly = t >> 4, lx = t & 15;
  int p = (y0 + ly) * IW + (x0 + lx);
  float acc[72];
#pragma unroll
  for (int c = 0; c < 72; ++c) {
    acc[c] = pwB1[c] + pwB2[c];
    if (MODE == 0) acc[c] += rpb[h * 9 + (c % 9)];
  }
#pragma unroll 1
  for (int d = 0; d < 8; ++d) {
#pragma unroll
    for (int t9 = 0; t9 < 9; ++t9) {               // static ky/kx, no div/mod
      const int ky = t9 / 3, kx = t9 % 3;
      const float v1 = dwa[d][ly + ky][lx + kx];
      const float v2 = dwb[d][ly + ky][lx + kx];
      const float* wp = wT + (size_t)(d * 9 + t9) * 144;   // uniform -> s_load
#pragma unroll
      for (int c = 0; c < 72; ++c) {               // 144-FMA burst per batch
        acc[c] = __builtin_fmaf(wp[c], v1, acc[c]);
        acc[c] = __builtin_fmaf(wp[72 + c], v2, acc[c]);
      }
    }
  }
  if (MODE == 0) {
    float q[8];
#pragma unroll
    for (int d = 0; d < 8; ++d) q[d] = f[((size_t)(bh * 24 + d)) * NPI + p];
    float e[9];
    float m = -1e30f;
#pragma unroll
    for (int kk = 0; kk < 9; ++kk) {
      float s = 0.f;
#pragma unroll
      for (int d = 0; d < 8; ++d) s = __builtin_fmaf(q[d], acc[d * 9 + kk], s);
      e[kk] = s;
      m = fmaxf(m, s);
    }
    float sum = 0.f;
#pragma unroll
    for (int kk = 0; kk < 9; ++kk) { e[kk] = __expf(e[kk] - m); sum += e[kk]; }
    float r = 1.f / sum;
#pragma unroll
    for (int kk = 0; kk < 9; ++kk)
      outp[((size_t)(bh * 9 + kk)) * NPI + p] = e[kk] * r;
  } else {
    float coef[9];
#pragma unroll
    for (int kk = 0; kk < 9; ++kk)
      coef[kk] = gout[((size_t)(bh * 9 + kk)) * NPI + p] +
                 attn_in[((size_t)(bh * 9 + kk)) * NPI + p];
#pragma unroll
    for (int d = 0; d < 8; ++d) {
      float s = 0.f;
#pragma unroll
      for (int kk = 0; kk < 9; ++kk) s = __builtin_fmaf(coef[kk], acc[d * 9 + kk], s);
      outp[((size_t)(bh * 8 + d)) * NPI + p] = s;
    }
  }
}

// ---------- K3: pin 1x1 conv 72->144, i-interleaved, acc[36] ----------
__global__ __launch_bounds__(256, 2) void k_pin(const float* __restrict__ attn,
                                                const float* __restrict__ pinT,
                                                const float* __restrict__ bias,
                                                float* __restrict__ fused) {
  int t = threadIdx.x, lane = t & 63;
  int wv = t >> 6;
  int gp = blockIdx.x * 64 + lane;
  int b = gp >> 14, p = gp & (NPI - 1);
  const float* ap = attn + (size_t)b * 72 * NPI + p;
  int jbase = wv * 36;
  float acc[36];
#pragma unroll
  for (int jj = 0; jj < 36; ++jj) acc[jj] = bias[jbase + jj];
#pragma unroll 2
  for (int i = 0; i < 72; ++i) {
    float ai = ap[(size_t)i * NPI];
    const float* wp = pinT + i * 144 + jbase;   // uniform -> s_load
#pragma unroll
    for (int jj = 0; jj < 36; ++jj)
      acc[jj] = __builtin_fmaf(wp[jj], ai, acc[jj]);
  }
#pragma unroll
  for (int jj = 0; jj < 36; ++jj)
    fused[((size_t)b * 144 + jbase + jj) * NPI + p] = acc[jj];
}

// ---------- K4: fused depthwise 7->relu->5->relu->3, 32x32 tiles ----------
__global__ __launch_bounds__(256) void k_dwchain(const float* __restrict__ fused,
    const float* __restrict__ w7, const float* __restrict__ b7,
    const float* __restrict__ w5, const float* __restrict__ b5,
    const float* __restrict__ w3, const float* __restrict__ b3,
    float* __restrict__ dwout) {
  __shared__ float s_in[44][44];
  __shared__ float s_t7[38][38];
  __shared__ float s_t5[34][34];
  int t = threadIdx.x;
  int tile = blockIdx.x;           // 0..15
  int c = blockIdx.y;              // 0..125
  int b = blockIdx.z;
  int y0 = (tile >> 2) << 5, x0 = (tile & 3) << 5;
  const float* src = fused + ((size_t)b * 144 + 18 + c) * NPI;
  for (int idx = t; idx < 44 * 44; idx += 256) {
    int yy = idx / 44, xx = idx % 44;
    int ay = y0 - 6 + yy, ax = x0 - 6 + xx;
    s_in[yy][xx] = ((unsigned)ay < (unsigned)IH && (unsigned)ax < (unsigned)IW)
                       ? src[ay * IW + ax] : 0.f;
  }
  __syncthreads();
  for (int idx = t; idx < 38 * 38; idx += 256) {
    int yy = idx / 38, xx = idx % 38;
    int ay = y0 - 3 + yy, ax = x0 - 3 + xx;
    float s = 0.f;
    if ((unsigned)ay < (unsigned)IH && (unsigned)ax < (unsigned)IW) {
      s = b7[c];
#pragma unroll
      for (int ky = 0; ky < 7; ++ky)
#pragma unroll
        for (int kx = 0; kx < 7; ++kx)
          s = __builtin_fmaf(w7[c * 49 + ky * 7 + kx], s_in[yy + ky][xx + kx], s);
      s = fmaxf(s, 0.f);
    }
    s_t7[yy][xx] = s;
  }
  __syncthreads();
  for (int idx = t; idx < 34 * 34; idx += 256) {
    int yy = idx / 34, xx = idx % 34;
    int ay = y0 - 1 + yy, ax = x0 - 1 + xx;
    float s = 0.f;
    if ((unsigned)ay < (unsigned)IH && (unsigned)ax < (unsigned)IW) {
      s = b5[c];
#pragma unroll
      for (int ky = 0; ky < 5; ++ky)
#pragma unroll
        for (int kx = 0; kx < 5; ++kx)
          s = __builtin_fmaf(w5[c * 25 + ky * 5 + kx], s_t7[yy + ky][xx + kx], s);
      s = fmaxf(s, 0.f);
    }
    s_t5[yy][xx] = s;
  }
  __syncthreads();
  for (int idx = t; idx < 32 * 32; idx += 256) {
    int py = idx >> 5, px = idx & 31;
    float s = b3[c];
#pragma unroll
    for (int ky = 0; ky < 3; ++ky)
#pragma unroll
      for (int kx = 0; kx < 3; ++kx)
        s = __builtin_fmaf(w3[c * 9 + ky * 3 + kx], s_t5[py + ky][px + kx], s);
    dwout[((size_t)b * 126 + c) * NPI + (y0 + py) * IW + (x0 + px)] = s;
  }
}

// ---------- K5: fused gate chain, i-interleaved phases, acc[<=18] ----------
__global__ __launch_bounds__(256, 2) void k_gchain(const float* __restrict__ fused,
    const float* __restrict__ dw,
    const float* __restrict__ pw1T, const float* __restrict__ pw1_b,
    const float* __restrict__ pw2T, const float* __restrict__ pw2_b,
    const float* __restrict__ poutT, const float* __restrict__ pout_b,
    float* __restrict__ gout) {
  __shared__ float t36[36][64];
  __shared__ float t72[72][64];
  int t = threadIdx.x, lane = t & 63;
  int wv = t >> 6;
  int gp = blockIdx.x * 64 + lane;
  int b = gp >> 14, p = gp & (NPI - 1);
  const float* fu = fused + (size_t)b * 144 * NPI + p;
  const float* dp = dw + (size_t)b * 126 * NPI + p;
  // phase A: g1 = pwa*d0 ; t36 = (pw1 g1 + b) * d1
  {
    int j0 = wv * 9;
    float acc[9];
#pragma unroll
    for (int j = 0; j < 9; ++j) acc[j] = pw1_b[j0 + j];
#pragma unroll
    for (int i = 0; i < 18; ++i) {
      float g1 = fu[(size_t)i * NPI] * dp[(size_t)i * NPI];
      const float* wp = pw1T + i * 36 + j0;    // uniform -> s_load
#pragma unroll
      for (int j = 0; j < 9; ++j) acc[j] = __builtin_fmaf(wp[j], g1, acc[j]);
    }
#pragma unroll
    for (int j = 0; j < 9; ++j)
      t36[j0 + j][lane] = acc[j] * dp[(size_t)(18 + j0 + j) * NPI];
  }
  __syncthreads();
  // phase B: t72 = (pw2 t36 + b) * d2
  {
    int j0 = wv * 18;
    float acc[18];
#pragma unroll
    for (int j = 0; j < 18; ++j) acc[j] = pw2_b[j0 + j];
#pragma unroll 2
    for (int i = 0; i < 36; ++i) {
      float ai = t36[i][lane];
      const float* wp = pw2T + i * 72 + j0;    // uniform -> s_load
#pragma unroll
      for (int j = 0; j < 18; ++j) acc[j] = __builtin_fmaf(wp[j], ai, acc[j]);
    }
#pragma unroll
    for (int j = 0; j < 18; ++j)
      t72[j0 + j][lane] = acc[j] * dp[(size_t)(54 + j0 + j) * NPI];
  }
  __syncthreads();
  // phase C: gout = pout t72 + b
  {
    int j0 = wv * 18;
    float acc[18];
#pragma unroll
    for (int j = 0; j < 18; ++j) acc[j] = pout_b[j0 + j];
#pragma unroll 2
    for (int i = 0; i < 72; ++i) {
      float ai = t72[i][lane];
      const float* wp = poutT + i * 72 + j0;   // uniform -> s_load
#pragma unroll
      for (int j = 0; j < 18; ++j) acc[j] = __builtin_fmaf(wp[j], ai, acc[j]);
    }
#pragma unroll
    for (int j = 0; j < 18; ++j)
      gout[((size_t)b * 72 + j0 + j) * NPI + p] = acc[j];
  }
}

// ---------- K9: proj GEMM, lane=co, acc[16 px], uniform pre via s_load ----------
__global__ __launch_bounds__(256, 2) void k_proj(const float* __restrict__ pre,
                                                 const float* __restrict__ w,
                                                 const float* __restrict__ bias,
                                                 float* __restrict__ out) {
  int t = threadIdx.x;                 // output channel 0..255
  int blk = blockIdx.x;                // 2048 blocks x 16 px
  int b = (blk * 16) >> 14;
  int p0 = (blk * 16) & (NPI - 1);
  const float* pp = pre + (size_t)b * 64 * NPI + p0;
  float acc[16];
  float bs = bias[t];
#pragma unroll
  for (int px = 0; px < 16; ++px) acc[px] = bs;
#pragma unroll 2
  for (int i = 0; i < 64; ++i) {
    float wv = w[i * 256 + t];                  // per-lane coalesced
    const float* sp = pp + (size_t)i * NPI;     // uniform -> s_load_dwordx16
#pragma unroll
    for (int px = 0; px < 16; ++px)
      acc[px] = __builtin_fmaf(wv, sp[px], acc[px]);
  }
#pragma unroll
  for (int px = 0; px < 16; ++px)
    out[((size_t)(b * NPI + p0 + px)) * 256 + t] = acc[px];
}

extern "C" void kernel_launch(void* const* d_in, const int* in_sizes, int n_in,
                              void* d_out, int out_size, void* d_ws, size_t ws_size,
                              hipStream_t stream) {
  const float* x        = (const float*)d_in[0];
  const float* qkv_w    = (const float*)d_in[1];
  const float* qkv_b    = (const float*)d_in[2];
  const float* dc1_dw_w = (const float*)d_in[3];
  const float* dc1_dw_b = (const float*)d_in[4];
  const float* dc1_pw_w = (const float*)d_in[5];
  const float* dc1_pw_b = (const float*)d_in[6];
  const float* dc2_dw_w = (const float*)d_in[7];
  const float* dc2_dw_b = (const float*)d_in[8];
  const float* dc2_pw_w = (const float*)d_in[9];
  const float* dc2_pw_b = (const float*)d_in[10];
  const float* rpb      = (const float*)d_in[11];
  const float* pin_w    = (const float*)d_in[12];
  const float* pin_b    = (const float*)d_in[13];
  const float* dw7_w    = (const float*)d_in[14];
  const float* dw7_b    = (const float*)d_in[15];
  const float* dw5_w    = (const float*)d_in[16];
  const float* dw5_b    = (const float*)d_in[17];
  const float* dw3_w    = (const float*)d_in[18];
  const float* dw3_b    = (const float*)d_in[19];
  const float* pw1_w    = (const float*)d_in[20];
  const float* pw1_b    = (const float*)d_in[21];
  const float* pw2_w    = (const float*)d_in[22];
  const float* pw2_b    = (const float*)d_in[23];
  const float* pout_w   = (const float*)d_in[24];
  const float* pout_b   = (const float*)d_in[25];
  const float* proj_w   = (const float*)d_in[26];
  const float* proj_b   = (const float*)d_in[27];
  (void)in_sizes; (void)n_in; (void)out_size; (void)ws_size;

  float* fbuf = (float*)d_out;          // qkv planar tensor, consumed before proj writes
  float* ws    = (float*)d_ws;
  float* wT    = ws;                    // 10368
  float* pinT  = wT + 10368;            // 10368
  float* pw1T  = pinT + 10368;          // 648
  float* pw2T  = pw1T + 648;            // 2592
  float* poutT = pw2T + 2592;           // 5184
  float* attn1 = poutT + 5184;          // 2359296
  float* fused = attn1 + 2359296;       // 4718592
  float* dwout = fused + 4718592;       // 4128768
  float* goutb = dwout + 4128768;       // 2359296
  float* pre   = goutb + 2359296;       // 2097152  -> total ~62.8 MB

  hipLaunchKernelGGL(k_wt, dim3(94), dim3(256), 0, stream, dc1_pw_w, dc2_pw_w,
                     pin_w, pw1_w, pw2_w, pout_w, wT, pinT, pw1T, pw2T, poutT);
  hipLaunchKernelGGL(k_qkv, dim3(512), dim3(512), 0, stream, x, qkv_w, qkv_b, fbuf);
  hipLaunchKernelGGL((k_dep<0>), dim3(64, 16), dim3(256), 0, stream, fbuf,
                     dc1_dw_w, dc1_dw_b, dc2_dw_w, dc2_dw_b, wT, dc1_pw_b, dc2_pw_b,
                     rpb, (const float*)nullptr, (const float*)nullptr, attn1);
  hipLaunchKernelGGL(k_pin, dim3(512), dim3(256), 0, stream, attn1, pinT, pin_b, fused);
  hipLaunchKernelGGL(k_dwchain, dim3(16, 126, 2), dim3(256), 0, stream, fused,
                     dw7_w, dw7_b, dw5_w, dw5_b, dw3_w, dw3_b, dwout);
  hipLaunchKernelGGL(k_gchain, dim3(512), dim3(256), 0, stream, fused, dwout,
                     pw1T, pw1_b, pw2T, pw2_b, poutT, pout_b, goutb);
  hipLaunchKernelGGL((k_dep<1>), dim3(64, 16), dim3(256), 0, stream, fbuf,
                     dc1_dw_w, dc1_dw_b, dc2_dw_w, dc2_dw_b, wT, dc1_pw_b, dc2_pw_b,
                     rpb, goutb, attn1, pre);
  hipLaunchKernelGGL(k_proj, dim3(2048), dim3(256), 0, stream, pre, proj_w, proj_b,
                     (float*)d_out);
}

// Round 12
// 482.146 us; speedup vs baseline: 2.3242x; 1.2547x over previous
//
#include <hip/hip_runtime.h>

#define IH 128
#define IW 128
#define NPI (IH*IW)   // 16384 pixels per image
// B=2, HEADS=8, D=8, KK=9, ATTN_DIM=72, DIMS={18,36,72}, SD=126

// ---------- K0: build transposed weight tables ----------
__global__ __launch_bounds__(256) void k_wt(const float* __restrict__ w1,
                                            const float* __restrict__ w2,
                                            const float* __restrict__ pin_w,
                                            const float* __restrict__ pw1_w,
                                            const float* __restrict__ pw2_w,
                                            const float* __restrict__ pout_w,
                                            float* __restrict__ wT,
                                            float* __restrict__ pinT,
                                            float* __restrict__ pw1T,
                                            float* __restrict__ pw2T,
                                            float* __restrict__ poutT) {
  int i = blockIdx.x * 256 + threadIdx.x;
  if (i < 5184) {                       // dc pw: 72x72, both branches
    int c = i / 72, dkk = i % 72;
    wT[dkk * 144 + c]      = w1[i];
    wT[dkk * 144 + 72 + c] = w2[i];
  } else if (i < 5184 + 10368) {        // pin 144x72
    int f = i - 5184;
    pinT[(f % 72) * 144 + f / 72] = pin_w[f];
  } else if (i < 5184 + 10368 + 648) {  // pw1 36x18
    int f = i - 5184 - 10368;
    pw1T[(f % 18) * 36 + f / 18] = pw1_w[f];
  } else if (i < 5184 + 10368 + 648 + 2592) {  // pw2 72x36
    int f = i - 5184 - 10368 - 648;
    pw2T[(f % 36) * 72 + f / 36] = pw2_w[f];
  } else if (i < 5184 + 10368 + 648 + 2592 + 5184) {  // pout 72x72
    int f = i - 5184 - 10368 - 648 - 2592;
    poutT[(f % 72) * 72 + f / 72] = pout_w[f];
  }
}

// ---------- K1: qkv GEMM, dual-LDS-tile, 4px x 12j register tile ----------
// M=32768 px, N=192, K=256. Block: 64 px x 192 j, K-chunk 16.
// No s_load in the hot loop: both operands via ds_read_b128 (broadcast / 2-way).
__global__ __launch_bounds__(256) void k_qkv(const float* __restrict__ x,
                                             const float* __restrict__ w,
                                             const float* __restrict__ bias,
                                             float* __restrict__ f) {
  __shared__ float xs[16][68];    // [k][px], pad 68 -> 16B-aligned rows, 2-way max
  __shared__ float ws[16][196];   // [k][j],  pad 196 -> 16B-aligned rows
  int t = threadIdx.x;
  int p0 = blockIdx.x * 64;
  int b = p0 >> 14;
  int pp = p0 & (NPI - 1);
  int tx = t & 15, ty = t >> 4;
  int pxb = tx * 4;               // 4 consecutive px
  int jb = ty * 12;               // 12 consecutive j
  float acc[48];
#pragma unroll
  for (int jj = 0; jj < 12; ++jj) {
    float bv = bias[jb + jj];
#pragma unroll
    for (int px = 0; px < 4; ++px) acc[jj * 4 + px] = bv;
  }
  // staging index precompute
  int spx = t >> 2;               // x stage: px row
  int sk = (t & 3) * 4;           // 4 consecutive k
#pragma unroll 1
  for (int c0 = 0; c0 < 256; c0 += 16) {
    // stage x chunk: 64px x 16k (coalesced float4 per thread)
    float4 xv = *reinterpret_cast<const float4*>(x + (size_t)(p0 + spx) * 256 + c0 + sk);
    xs[sk + 0][spx] = xv.x;
    xs[sk + 1][spx] = xv.y;
    xs[sk + 2][spx] = xv.z;
    xs[sk + 3][spx] = xv.w;
    // stage w chunk: 16k x 192j = 768 float4, 3 per thread, fully coalesced
#pragma unroll
    for (int r = 0; r < 3; ++r) {
      int flat = (r * 256 + t) * 4;          // float index into 16x192 tile
      int kk = flat / 192, jj = flat % 192;
      float4 wv = *reinterpret_cast<const float4*>(w + (size_t)(c0 + kk) * 192 + jj);
      *reinterpret_cast<float4*>(&ws[kk][jj]) = wv;
    }
    __syncthreads();
#pragma unroll 4
    for (int k = 0; k < 16; ++k) {
      float4 xr = *reinterpret_cast<const float4*>(&xs[k][pxb]);
      float4 w0 = *reinterpret_cast<const float4*>(&ws[k][jb]);
      float4 w1 = *reinterpret_cast<const float4*>(&ws[k][jb + 4]);
      float4 w2 = *reinterpret_cast<const float4*>(&ws[k][jb + 8]);
      const float xv4[4] = {xr.x, xr.y, xr.z, xr.w};
      const float wv12[12] = {w0.x, w0.y, w0.z, w0.w, w1.x, w1.y, w1.z, w1.w,
                              w2.x, w2.y, w2.z, w2.w};
#pragma unroll
      for (int jj = 0; jj < 12; ++jj)
#pragma unroll
        for (int px = 0; px < 4; ++px)
          acc[jj * 4 + px] = __builtin_fmaf(wv12[jj], xv4[px], acc[jj * 4 + px]);
    }
    __syncthreads();
  }
#pragma unroll
  for (int jj = 0; jj < 12; ++jj) {
    float4 o;
    o.x = acc[jj * 4 + 0]; o.y = acc[jj * 4 + 1];
    o.z = acc[jj * 4 + 2]; o.w = acc[jj * 4 + 3];
    *reinterpret_cast<float4*>(
        &f[((size_t)(b * 192 + jb + jj)) * NPI + pp + pxb]) = o;
  }
}

// ---------- K2/K8: dep() fused with consumer ----------
// 256 thr, 1 px/thread, acc[72], 144-FMA bursts per s_load batch. (256,1): no spill.
template <int MODE>
__global__ __launch_bounds__(256, 1) void k_dep(const float* __restrict__ f,
    const float* __restrict__ dwW1, const float* __restrict__ dwB1,
    const float* __restrict__ dwW2, const float* __restrict__ dwB2,
    const float* __restrict__ wT,  const float* __restrict__ pwB1,
    const float* __restrict__ pwB2, const float* __restrict__ rpb,
    const float* __restrict__ gout, const float* __restrict__ attn_in,
    float* __restrict__ outp) {
  __shared__ float kin[8][20][20];
  __shared__ float dwa[8][18][20];   // pad stride 20 (2-way conflicts are free)
  __shared__ float dwb[8][18][20];
  int t = threadIdx.x;
  int tile = blockIdx.x;
  int bh = blockIdx.y;
  int h = bh & 7;
  int y0 = (tile >> 3) << 4, x0 = (tile & 7) << 4;
  const float* src = f + ((size_t)(bh * 24 + (MODE ? 16 : 8))) * NPI;
  for (int idx = t; idx < 8 * 20 * 20; idx += 256) {
    int c = idx / 400, r = idx % 400, yy = r / 20, xx = r % 20;
    int ay = y0 - 2 + yy, ax = x0 - 2 + xx;
    float v = 0.f;
    if ((unsigned)ay < (unsigned)IH && (unsigned)ax < (unsigned)IW)
      v = src[c * NPI + ay * IW + ax];
    kin[c][yy][xx] = v;
  }
  __syncthreads();
  for (int idx = t; idx < 8 * 18 * 18; idx += 256) {
    int c = idx / 324, r = idx % 324, yy = r / 18, xx = r % 18;
    int ay = y0 - 1 + yy, ax = x0 - 1 + xx;
    float va = 0.f, vb = 0.f;
    if ((unsigned)ay < (unsigned)IH && (unsigned)ax < (unsigned)IW) {
      va = dwB1[c]; vb = dwB2[c];
#pragma unroll
      for (int ky = 0; ky < 3; ++ky)
#pragma unroll
        for (int kx = 0; kx < 3; ++kx) {
          float s = kin[c][yy + ky][xx + kx];
          va = __builtin_fmaf(dwW1[c * 9 + ky * 3 + kx], s, va);
          vb = __builtin_fmaf(dwW2[c * 9 + ky * 3 + kx], s, vb);
        }
    }
    dwa[c][yy][xx] = va;
    dwb[c][yy][xx] = vb;
  }
  __syncthreads();
  int ly = t >> 4, lx = t & 15;
  int p = (y0 + ly) * IW + (x0 + lx);
  float acc[72];
#pragma unroll
  for (int c = 0; c < 72; ++c) {
    acc[c] = pwB1[c] + pwB2[c];
    if (MODE == 0) acc[c] += rpb[h * 9 + (c % 9)];
  }
#pragma unroll 1
  for (int d = 0; d < 8; ++d) {
#pragma unroll
    for (int t9 = 0; t9 < 9; ++t9) {               // static ky/kx, no div/mod
      const int ky = t9 / 3, kx = t9 % 3;
      const float v1 = dwa[d][ly + ky][lx + kx];
      const float v2 = dwb[d][ly + ky][lx + kx];
      const float* wp = wT + (size_t)(d * 9 + t9) * 144;   // uniform -> s_load
#pragma unroll
      for (int c = 0; c < 72; ++c) {               // 144-FMA burst per batch
        acc[c] = __builtin_fmaf(wp[c], v1, acc[c]);
        acc[c] = __builtin_fmaf(wp[72 + c], v2, acc[c]);
      }
    }
  }
  if (MODE == 0) {
    float q[8];
#pragma unroll
    for (int d = 0; d < 8; ++d) q[d] = f[((size_t)(bh * 24 + d)) * NPI + p];
    float e[9];
    float m = -1e30f;
#pragma unroll
    for (int kk = 0; kk < 9; ++kk) {
      float s = 0.f;
#pragma unroll
      for (int d = 0; d < 8; ++d) s = __builtin_fmaf(q[d], acc[d * 9 + kk], s);
      e[kk] = s;
      m = fmaxf(m, s);
    }
    float sum = 0.f;
#pragma unroll
    for (int kk = 0; kk < 9; ++kk) { e[kk] = __expf(e[kk] - m); sum += e[kk]; }
    float r = 1.f / sum;
#pragma unroll
    for (int kk = 0; kk < 9; ++kk)
      outp[((size_t)(bh * 9 + kk)) * NPI + p] = e[kk] * r;
  } else {
    float coef[9];
#pragma unroll
    for (int kk = 0; kk < 9; ++kk)
      coef[kk] = gout[((size_t)(bh * 9 + kk)) * NPI + p] +
                 attn_in[((size_t)(bh * 9 + kk)) * NPI + p];
#pragma unroll
    for (int d = 0; d < 8; ++d) {
      float s = 0.f;
#pragma unroll
      for (int kk = 0; kk < 9; ++kk) s = __builtin_fmaf(coef[kk], acc[d * 9 + kk], s);
      outp[((size_t)(bh * 8 + d)) * NPI + p] = s;
    }
  }
}

// ---------- K3: pin 1x1 conv 72->144, i-interleaved, acc[36] ----------
__global__ __launch_bounds__(256, 2) void k_pin(const float* __restrict__ attn,
                                                const float* __restrict__ pinT,
                                                const float* __restrict__ bias,
                                                float* __restrict__ fused) {
  int t = threadIdx.x, lane = t & 63;
  int wv = t >> 6;
  int gp = blockIdx.x * 64 + lane;
  int b = gp >> 14, p = gp & (NPI - 1);
  const float* ap = attn + (size_t)b * 72 * NPI + p;
  int jbase = wv * 36;
  float acc[36];
#pragma unroll
  for (int jj = 0; jj < 36; ++jj) acc[jj] = bias[jbase + jj];
#pragma unroll 2
  for (int i = 0; i < 72; ++i) {
    float ai = ap[(size_t)i * NPI];
    const float* wp = pinT + i * 144 + jbase;   // uniform -> s_load
#pragma unroll
    for (int jj = 0; jj < 36; ++jj)
      acc[jj] = __builtin_fmaf(wp[jj], ai, acc[jj]);
  }
#pragma unroll
  for (int jj = 0; jj < 36; ++jj)
    fused[((size_t)b * 144 + jbase + jj) * NPI + p] = acc[jj];
}

// ---------- K4: fused depthwise 7->relu->5->relu->3, 32x32 tiles ----------
__global__ __launch_bounds__(256) void k_dwchain(const float* __restrict__ fused,
    const float* __restrict__ w7, const float* __restrict__ b7,
    const float* __restrict__ w5, const float* __restrict__ b5,
    const float* __restrict__ w3, const float* __restrict__ b3,
    float* __restrict__ dwout) {
  __shared__ float s_in[44][44];
  __shared__ float s_t7[38][38];
  __shared__ float s_t5[34][34];
  int t = threadIdx.x;
  int tile = blockIdx.x;           // 0..15
  int c = blockIdx.y;              // 0..125
  int b = blockIdx.z;
  int y0 = (tile >> 2) << 5, x0 = (tile & 3) << 5;
  const float* src = fused + ((size_t)b * 144 + 18 + c) * NPI;
  for (int idx = t; idx < 44 * 44; idx += 256) {
    int yy = idx / 44, xx = idx % 44;
    int ay = y0 - 6 + yy, ax = x0 - 6 + xx;
    s_in[yy][xx] = ((unsigned)ay < (unsigned)IH && (unsigned)ax < (unsigned)IW)
                       ? src[ay * IW + ax] : 0.f;
  }
  __syncthreads();
  for (int idx = t; idx < 38 * 38; idx += 256) {
    int yy = idx / 38, xx = idx % 38;
    int ay = y0 - 3 + yy, ax = x0 - 3 + xx;
    float s = 0.f;
    if ((unsigned)ay < (unsigned)IH && (unsigned)ax < (unsigned)IW) {
      s = b7[c];
#pragma unroll
      for (int ky = 0; ky < 7; ++ky)
#pragma unroll
        for (int kx = 0; kx < 7; ++kx)
          s = __builtin_fmaf(w7[c * 49 + ky * 7 + kx], s_in[yy + ky][xx + kx], s);
      s = fmaxf(s, 0.f);
    }
    s_t7[yy][xx] = s;
  }
  __syncthreads();
  for (int idx = t; idx < 34 * 34; idx += 256) {
    int yy = idx / 34, xx = idx % 34;
    int ay = y0 - 1 + yy, ax = x0 - 1 + xx;
    float s = 0.f;
    if ((unsigned)ay < (unsigned)IH && (unsigned)ax < (unsigned)IW) {
      s = b5[c];
#pragma unroll
      for (int ky = 0; ky < 5; ++ky)
#pragma unroll
        for (int kx = 0; kx < 5; ++kx)
          s = __builtin_fmaf(w5[c * 25 + ky * 5 + kx], s_t7[yy + ky][xx + kx], s);
      s = fmaxf(s, 0.f);
    }
    s_t5[yy][xx] = s;
  }
  __syncthreads();
  for (int idx = t; idx < 32 * 32; idx += 256) {
    int py = idx >> 5, px = idx & 31;
    float s = b3[c];
#pragma unroll
    for (int ky = 0; ky < 3; ++ky)
#pragma unroll
      for (int kx = 0; kx < 3; ++kx)
        s = __builtin_fmaf(w3[c * 9 + ky * 3 + kx], s_t5[py + ky][px + kx], s);
    dwout[((size_t)b * 126 + c) * NPI + (y0 + py) * IW + (x0 + px)] = s;
  }
}

// ---------- K5: fused gate chain, i-interleaved phases, acc[<=18] ----------
__global__ __launch_bounds__(256, 2) void k_gchain(const float* __restrict__ fused,
    const float* __restrict__ dw,
    const float* __restrict__ pw1T, const float* __restrict__ pw1_b,
    const float* __restrict__ pw2T, const float* __restrict__ pw2_b,
    const float* __restrict__ poutT, const float* __restrict__ pout_b,
    float* __restrict__ gout) {
  __shared__ float t36[36][64];
  __shared__ float t72[72][64];
  int t = threadIdx.x, lane = t & 63;
  int wv = t >> 6;
  int gp = blockIdx.x * 64 + lane;
  int b = gp >> 14, p = gp & (NPI - 1);
  const float* fu = fused + (size_t)b * 144 * NPI + p;
  const float* dp = dw + (size_t)b * 126 * NPI + p;
  // phase A: g1 = pwa*d0 ; t36 = (pw1 g1 + b) * d1
  {
    int j0 = wv * 9;
    float acc[9];
#pragma unroll
    for (int j = 0; j < 9; ++j) acc[j] = pw1_b[j0 + j];
#pragma unroll
    for (int i = 0; i < 18; ++i) {
      float g1 = fu[(size_t)i * NPI] * dp[(size_t)i * NPI];
      const float* wp = pw1T + i * 36 + j0;    // uniform -> s_load
#pragma unroll
      for (int j = 0; j < 9; ++j) acc[j] = __builtin_fmaf(wp[j], g1, acc[j]);
    }
#pragma unroll
    for (int j = 0; j < 9; ++j)
      t36[j0 + j][lane] = acc[j] * dp[(size_t)(18 + j0 + j) * NPI];
  }
  __syncthreads();
  // phase B: t72 = (pw2 t36 + b) * d2
  {
    int j0 = wv * 18;
    float acc[18];
#pragma unroll
    for (int j = 0; j < 18; ++j) acc[j] = pw2_b[j0 + j];
#pragma unroll 2
    for (int i = 0; i < 36; ++i) {
      float ai = t36[i][lane];
      const float* wp = pw2T + i * 72 + j0;    // uniform -> s_load
#pragma unroll
      for (int j = 0; j < 18; ++j) acc[j] = __builtin_fmaf(wp[j], ai, acc[j]);
    }
#pragma unroll
    for (int j = 0; j < 18; ++j)
      t72[j0 + j][lane] = acc[j] * dp[(size_t)(54 + j0 + j) * NPI];
  }
  __syncthreads();
  // phase C: gout = pout t72 + b
  {
    int j0 = wv * 18;
    float acc[18];
#pragma unroll
    for (int j = 0; j < 18; ++j) acc[j] = pout_b[j0 + j];
#pragma unroll 2
    for (int i = 0; i < 72; ++i) {
      float ai = t72[i][lane];
      const float* wp = poutT + i * 72 + j0;   // uniform -> s_load
#pragma unroll
      for (int j = 0; j < 18; ++j) acc[j] = __builtin_fmaf(wp[j], ai, acc[j]);
    }
#pragma unroll
    for (int j = 0; j < 18; ++j)
      gout[((size_t)b * 72 + j0 + j) * NPI + p] = acc[j];
  }
}

// ---------- K9: proj GEMM, lane=co, acc[16 px], uniform pre via s_load ----------
__global__ __launch_bounds__(256, 2) void k_proj(const float* __restrict__ pre,
                                                 const float* __restrict__ w,
                                                 const float* __restrict__ bias,
                                                 float* __restrict__ out) {
  int t = threadIdx.x;                 // output channel 0..255
  int blk = blockIdx.x;                // 2048 blocks x 16 px
  int b = (blk * 16) >> 14;
  int p0 = (blk * 16) & (NPI - 1);
  const float* pp = pre + (size_t)b * 64 * NPI + p0;
  float acc[16];
  float bs = bias[t];
#pragma unroll
  for (int px = 0; px < 16; ++px) acc[px] = bs;
#pragma unroll 2
  for (int i = 0; i < 64; ++i) {
    float wv = w[i * 256 + t];                  // per-lane coalesced
    const float* sp = pp + (size_t)i * NPI;     // uniform -> s_load_dwordx16
#pragma unroll
    for (int px = 0; px < 16; ++px)
      acc[px] = __builtin_fmaf(wv, sp[px], acc[px]);
  }
#pragma unroll
  for (int px = 0; px < 16; ++px)
    out[((size_t)(b * NPI + p0 + px)) * 256 + t] = acc[px];
}

extern "C" void kernel_launch(void* const* d_in, const int* in_sizes, int n_in,
                              void* d_out, int out_size, void* d_ws, size_t ws_size,
                              hipStream_t stream) {
  const float* x        = (const float*)d_in[0];
  const float* qkv_w    = (const float*)d_in[1];
  const float* qkv_b    = (const float*)d_in[2];
  const float* dc1_dw_w = (const float*)d_in[3];
  const float* dc1_dw_b = (const float*)d_in[4];
  const float* dc1_pw_w = (const float*)d_in[5];
  const float* dc1_pw_b = (const float*)d_in[6];
  const float* dc2_dw_w = (const float*)d_in[7];
  const float* dc2_dw_b = (const float*)d_in[8];
  const float* dc2_pw_w = (const float*)d_in[9];
  const float* dc2_pw_b = (const float*)d_in[10];
  const float* rpb      = (const float*)d_in[11];
  const float* pin_w    = (const float*)d_in[12];
  const float* pin_b    = (const float*)d_in[13];
  const float* dw7_w    = (const float*)d_in[14];
  const float* dw7_b    = (const float*)d_in[15];
  const float* dw5_w    = (const float*)d_in[16];
  const float* dw5_b    = (const float*)d_in[17];
  const float* dw3_w    = (const float*)d_in[18];
  const float* dw3_b    = (const float*)d_in[19];
  const float* pw1_w    = (const float*)d_in[20];
  const float* pw1_b    = (const float*)d_in[21];
  const float* pw2_w    = (const float*)d_in[22];
  const float* pw2_b    = (const float*)d_in[23];
  const float* pout_w   = (const float*)d_in[24];
  const float* pout_b   = (const float*)d_in[25];
  const float* proj_w   = (const float*)d_in[26];
  const float* proj_b   = (const float*)d_in[27];
  (void)in_sizes; (void)n_in; (void)out_size; (void)ws_size;

  float* fbuf = (float*)d_out;          // qkv planar tensor, consumed before proj writes
  float* ws    = (float*)d_ws;
  float* wT    = ws;                    // 10368
  float* pinT  = wT + 10368;            // 10368
  float* pw1T  = pinT + 10368;          // 648
  float* pw2T  = pw1T + 648;            // 2592
  float* poutT = pw2T + 2592;           // 5184
  float* attn1 = poutT + 5184;          // 2359296
  float* fused = attn1 + 2359296;       // 4718592
  float* dwout = fused + 4718592;       // 4128768
  float* goutb = dwout + 4128768;       // 2359296
  float* pre   = goutb + 2359296;       // 2097152  -> total ~62.8 MB

  hipLaunchKernelGGL(k_wt, dim3(94), dim3(256), 0, stream, dc1_pw_w, dc2_pw_w,
                     pin_w, pw1_w, pw2_w, pout_w, wT, pinT, pw1T, pw2T, poutT);
  hipLaunchKernelGGL(k_qkv, dim3(512), dim3(256), 0, stream, x, qkv_w, qkv_b, fbuf);
  hipLaunchKernelGGL((k_dep<0>), dim3(64, 16), dim3(256), 0, stream, fbuf,
                     dc1_dw_w, dc1_dw_b, dc2_dw_w, dc2_dw_b, wT, dc1_pw_b, dc2_pw_b,
                     rpb, (const float*)nullptr, (const float*)nullptr, attn1);
  hipLaunchKernelGGL(k_pin, dim3(512), dim3(256), 0, stream, attn1, pinT, pin_b, fused);
  hipLaunchKernelGGL(k_dwchain, dim3(16, 126, 2), dim3(256), 0, stream, fused,
                     dw7_w, dw7_b, dw5_w, dw5_b, dw3_w, dw3_b, dwout);
  hipLaunchKernelGGL(k_gchain, dim3(512), dim3(256), 0, stream, fused, dwout,
                     pw1T, pw1_b, pw2T, pw2_b, poutT, pout_b, goutb);
  hipLaunchKernelGGL((k_dep<1>), dim3(64, 16), dim3(256), 0, stream, fbuf,
                     dc1_dw_w, dc1_dw_b, dc2_dw_w, dc2_dw_b, wT, dc1_pw_b, dc2_pw_b,
                     rpb, goutb, attn1, pre);
  hipLaunchKernelGGL(k_proj, dim3(2048), dim3(256), 0, stream, pre, proj_w, proj_b,
                     (float*)d_out);
}